// Round 6
// baseline (11748.803 us; speedup 1.0000x reference)
//
#include <hip/hip_runtime.h>
#include <hip/hip_bf16.h>
#include <math.h>

// Problem constants
constexpr int B = 64, T = 128, D = 512, L = 9, S = 64;
constexpr int G = 4 * D;      // 2048 gate rows per layer
constexpr int NBLK = L * 32;  // 288 persistent blocks

typedef __attribute__((ext_vector_type(8))) short short8;          // 8 bf16 = 4 VGPR
typedef __attribute__((ext_vector_type(8))) unsigned short ushort8;
typedef __attribute__((ext_vector_type(4))) float f32x4;

// ---------------------------------------------------------------------------
// Workspace layout (bytes):
//  Wpk  [L][2048][1024] bf16  rows remapped rr=4*d+gate; k<512=W_ih, k>=512=W_hh
//  bpk  [L][2048] f32         same row remap
//  hemb [T][B][D] bf16
//  hbuf [L][2][B][D] bf16     parity ping-pong h state per layer
//  hfin [T][B][D] f32         layer-8 h history (feeds LayerNorm)
//  cnt  [1] u32               grid barrier ticket counter
// ---------------------------------------------------------------------------
constexpr size_t WPK_BYTES  = (size_t)L * 2048 * 1024 * 2;   // 37,748,736
constexpr size_t BPK_BYTES  = (size_t)L * 2048 * 4;          // 73,728
constexpr size_t HEMB_BYTES = (size_t)T * B * D * 2;         // 8,388,608
constexpr size_t HBUF_BYTES = (size_t)L * 2 * B * D * 2;     // 1,179,648
constexpr size_t HFIN_BYTES = (size_t)T * B * D * 4;         // 16,777,216

// ---------------------------------------------------------------------------
// K0: pack weights+bias to bf16, fused [ih|hh] K-space, remapped rows.
// ---------------------------------------------------------------------------
__global__ __launch_bounds__(256) void k_pack(const float* __restrict__ W_ih,
                                              const float* __restrict__ W_hh,
                                              const float* __restrict__ bsrc,
                                              unsigned short* __restrict__ Wpk,
                                              float* __restrict__ bpk) {
    int rr = blockIdx.x;
    int l  = rr >> 11;
    int rl = rr & 2047;
    int g  = rl & 3, dd = rl >> 2;
    int srow = g * D + dd;  // source row within layer (gate-major)
    int k = threadIdx.x * 4;
    const float* src = (k < D) ? (W_ih + ((size_t)l * G + srow) * D + k)
                               : (W_hh + ((size_t)l * G + srow) * D + (k - D));
    float4 v = *(const float4*)src;
    __hip_bfloat16 b0 = __float2bfloat16(v.x), b1 = __float2bfloat16(v.y),
                   b2 = __float2bfloat16(v.z), b3 = __float2bfloat16(v.w);
    ushort4 pk;
    pk.x = *(unsigned short*)&b0; pk.y = *(unsigned short*)&b1;
    pk.z = *(unsigned short*)&b2; pk.w = *(unsigned short*)&b3;
    *(ushort4*)(Wpk + ((size_t)l * 2048 + rl) * 1024 + k) = pk;
    if (threadIdx.x == 0) bpk[(size_t)l * 2048 + rl] = bsrc[(size_t)l * G + srow];
}

// ---------------------------------------------------------------------------
// K1a: zero the grid-barrier counter (each call: deterministic across replays)
// ---------------------------------------------------------------------------
__global__ void k_zero(unsigned* __restrict__ cnt) { *cnt = 0u; }

// ---------------------------------------------------------------------------
// K1: embedding gather -> hemb [t][b][d] bf16.
// ---------------------------------------------------------------------------
__global__ __launch_bounds__(256) void k_embed(const int* __restrict__ x,
                                               const float* __restrict__ emb,
                                               unsigned short* __restrict__ hemb) {
    int row = blockIdx.x * 2 + (threadIdx.x >> 7);  // row = t*B + b
    int t = row >> 6, b = row & 63;
    int d0 = (threadIdx.x & 127) * 4;
    int xi = x[b * T + t];
    float4 v = *(const float4*)(emb + (size_t)xi * D + d0);
    __hip_bfloat16 b0 = __float2bfloat16(v.x), b1 = __float2bfloat16(v.y),
                   b2 = __float2bfloat16(v.z), b3 = __float2bfloat16(v.w);
    ushort4 pk;
    pk.x = *(unsigned short*)&b0; pk.y = *(unsigned short*)&b1;
    pk.z = *(unsigned short*)&b2; pk.w = *(unsigned short*)&b3;
    *(ushort4*)(hemb + (size_t)row * D + d0) = pk;
}

// ---------------------------------------------------------------------------
// Device-scope ticket barrier (sense-free, monotonic counter).
// All NBLK blocks call it once per diagonal; target = NBLK*(iter+1).
// atomicAdd on global is device-scope by default; acquire-load spin with
// s_sleep; L1 invalidation comes from the acquire semantics.
// ---------------------------------------------------------------------------
__device__ __forceinline__ void grid_barrier(unsigned* __restrict__ cnt,
                                             unsigned target) {
    __syncthreads();
    if (threadIdx.x == 0) {
        __threadfence();          // release prior stores device-wide
        atomicAdd(cnt, 1u);
        while (__hip_atomic_load(cnt, __ATOMIC_ACQUIRE,
                                 __HIP_MEMORY_SCOPE_AGENT) < target) {
            __builtin_amdgcn_s_sleep(2);
        }
    }
    __syncthreads();
}

// ---------------------------------------------------------------------------
// K2: persistent scan kernel (plain launch + own grid barrier).
// Grid = 288 blocks x 64 threads. Block = one wave, pinned to (l = bid>>5,
// bt = bid&31): output tile = 64 batches x 64 wrows (wrows [bt*64, bt*64+64)).
// Per diagonal d (= l + t), active blocks run one cell step; grid_barrier
// separates diagonals (parity-2 h buffers are race-free under lockstep).
//
// Main loop: NO LDS. 2-deep register ring of W/h fragments loaded with
// global_load_dwordx4 (16 loads/step of BK=64); 32 MFMA/step.
// MFMA operand order (A=wf, B=hf) => C[row=wrow][col=batch]: the f32x4 acc
// regs j=0..3 are gates i,f,g,o of cell (dd = bt*16+wc*4+fq, bb = rt*16+fr)
// -- no cross-lane transpose, and c-state stays in registers for all 128 t.
// ---------------------------------------------------------------------------
struct Frags {
    short8 h[2][4];  // [kc][rt]
    short8 w[2][4];  // [kc][wc]
};

__device__ __forceinline__ Frags load_step(const unsigned short* __restrict__ hb,
                                           const unsigned short* __restrict__ hp,
                                           const unsigned short* __restrict__ wbase,
                                           int k0, int fr, int fq) {
    Frags f;
    const unsigned short* hx = (k0 < D) ? hb : hp;
    const int kk = (k0 & (D - 1)) + fq * 8;
#pragma unroll
    for (int kc = 0; kc < 2; kc++) {
#pragma unroll
        for (int rt = 0; rt < 4; rt++)
            f.h[kc][rt] = *(const short8*)(hx + (size_t)(rt * 16 + fr) * D + kk + kc * 32);
#pragma unroll
        for (int wc = 0; wc < 4; wc++)
            f.w[kc][wc] = *(const short8*)(wbase + (size_t)(wc * 16 + fr) * 1024 +
                                           k0 + kc * 32 + fq * 8);
    }
    return f;
}

__device__ __forceinline__ void compute_step(f32x4 acc[4][4], const Frags& f) {
#pragma unroll
    for (int kc = 0; kc < 2; kc++)
#pragma unroll
        for (int wc = 0; wc < 4; wc++)
#pragma unroll
            for (int rt = 0; rt < 4; rt++)
                acc[rt][wc] = __builtin_amdgcn_mfma_f32_16x16x32_bf16(
                    f.w[kc][wc], f.h[kc][rt], acc[rt][wc], 0, 0, 0);
}

template <int NS>
__device__ __forceinline__ void gemm_pipe(f32x4 acc[4][4],
                                          const unsigned short* __restrict__ hb,
                                          const unsigned short* __restrict__ hp,
                                          const unsigned short* __restrict__ wbase,
                                          int fr, int fq) {
    Frags cur = load_step(hb, hp, wbase, 0, fr, fq);
#pragma unroll 2
    for (int s = 0; s < NS - 1; ++s) {
        Frags nxt = load_step(hb, hp, wbase, (s + 1) * 64, fr, fq);
        compute_step(acc, cur);
        cur = nxt;
    }
    compute_step(acc, cur);
}

__global__ __launch_bounds__(64) void k_scan(const unsigned short* __restrict__ Wpk,
                                             const float* __restrict__ bpk,
                                             const unsigned short* __restrict__ hemb,
                                             unsigned short* __restrict__ hbuf,
                                             float* __restrict__ hfin,
                                             unsigned* __restrict__ cnt) {
    const int bid = blockIdx.x;
    const int l   = bid >> 5;   // layer 0..8
    const int bt  = bid & 31;   // row chunk
    const int lane = threadIdx.x;
    const int fr = lane & 15, fq = lane >> 4;

    const unsigned short* wbase = Wpk + ((size_t)l * 2048 + (size_t)bt * 64) * 1024;

    // bias: dd = bt*16 + wc*4 + fq, 4 gates each (constant per block+lane)
    float4 bias4[4];
#pragma unroll
    for (int wc = 0; wc < 4; wc++)
        bias4[wc] = *(const float4*)(bpk + (size_t)l * 2048 + ((bt * 16 + wc * 4 + fq) << 2));

    float c_reg[4][4];
#pragma unroll
    for (int i = 0; i < 4; i++)
#pragma unroll
        for (int j = 0; j < 4; j++) c_reg[i][j] = 0.f;

    __shared__ unsigned short hst[64][16];  // bf16 h staging for coalesced store
    __shared__ float fst[64][16];           // f32 staging for hfin (l==8)

    for (int d = 0; d <= (L - 1) + (T - 1); ++d) {
        const int t = d - l;
        if (t >= 0 && t < T) {
            const unsigned short* hb = (l == 0)
                ? (hemb + (size_t)t * B * D)
                : (hbuf + ((size_t)(l - 1) * 2 + (t & 1)) * B * D);
            const unsigned short* hp = hbuf + ((size_t)l * 2 + ((t - 1) & 1)) * B * D;

            f32x4 acc[4][4];
#pragma unroll
            for (int i = 0; i < 4; i++)
#pragma unroll
                for (int j = 0; j < 4; j++) acc[i][j] = f32x4{0.f, 0.f, 0.f, 0.f};

            if (t > 0) gemm_pipe<16>(acc, hb, hp, wbase, fr, fq);
            else       gemm_pipe<8>(acc, hb, hp, wbase, fr, fq);

            // Epilogue: acc[rt][wc] = (i,f,g,o) of cell (dd, bb) in-lane.
            unsigned short* hout = hbuf + ((size_t)l * 2 + (t & 1)) * B * D;
#pragma unroll
            for (int rt = 0; rt < 4; rt++) {
#pragma unroll
                for (int wc = 0; wc < 4; wc++) {
                    float gi = acc[rt][wc].x + bias4[wc].x;
                    float gf = acc[rt][wc].y + bias4[wc].y;
                    float gg = acc[rt][wc].z + bias4[wc].z;
                    float go = acc[rt][wc].w + bias4[wc].w;
                    float si = 1.f / (1.f + __expf(-gi));
                    float sf = 1.f / (1.f + __expf(-gf));
                    float so = 1.f / (1.f + __expf(-go));
                    float tg = tanhf(gg);
                    float cn = (t > 0) ? fmaf(sf, c_reg[rt][wc], si * tg) : (si * tg);
                    c_reg[rt][wc] = cn;
                    float hv = so * tanhf(cn);
                    __hip_bfloat16 hvb = __float2bfloat16(hv);
                    hst[rt * 16 + fr][wc * 4 + fq] = *(unsigned short*)&hvb;
                    if (l == 8) fst[rt * 16 + fr][wc * 4 + fq] = hv;
                }
            }
            __syncthreads();
            // Coalesced store: lane = batch row, 16 dd values = 32 B
            {
                ushort8 r0 = *(const ushort8*)&hst[lane][0];
                ushort8 r1 = *(const ushort8*)&hst[lane][8];
                unsigned short* dst = hout + (size_t)lane * D + bt * 16;
                *(ushort8*)dst = r0;
                *(ushort8*)(dst + 8) = r1;
            }
            if (l == 8) {
                float* dst = hfin + ((size_t)t * B + lane) * D + bt * 16;
#pragma unroll
                for (int j = 0; j < 4; j++)
                    *(float4*)(dst + j * 4) = *(const float4*)&fst[lane][j * 4];
            }
        }
        grid_barrier(cnt, (unsigned)NBLK * (unsigned)(d + 1));
    }
}

// ---------------------------------------------------------------------------
// K3: LayerNorm.  hfin [t*B+b][D] f32 -> hn [b*T+t][D] f32.  1 wave per row.
// ---------------------------------------------------------------------------
__global__ __launch_bounds__(256) void k_ln(const float* __restrict__ hfin,
                                            const float* __restrict__ gamma,
                                            const float* __restrict__ beta,
                                            float* __restrict__ hn) {
    int row  = blockIdx.x * 4 + (threadIdx.x >> 6);  // t*B + b
    int lane = threadIdx.x & 63;
    int t = row >> 6, b = row & 63;
    const float* in = hfin + (size_t)row * D;
    float4 a = *((const float4*)in + lane * 2);
    float4 c = *((const float4*)in + lane * 2 + 1);
    float s1 = a.x + a.y + a.z + a.w + c.x + c.y + c.z + c.w;
    float s2 = a.x * a.x + a.y * a.y + a.z * a.z + a.w * a.w +
               c.x * c.x + c.y * c.y + c.z * c.z + c.w * c.w;
#pragma unroll
    for (int m = 1; m < 64; m <<= 1) {
        s1 += __shfl_xor(s1, m);
        s2 += __shfl_xor(s2, m);
    }
    float mean = s1 / D;
    float rstd = rsqrtf(s2 / D - mean * mean + 1e-5f);
    float4 g0 = *((const float4*)gamma + lane * 2);
    float4 g1 = *((const float4*)gamma + lane * 2 + 1);
    float4 be0 = *((const float4*)beta + lane * 2);
    float4 be1 = *((const float4*)beta + lane * 2 + 1);
    float4 o0, o1;
    o0.x = fmaf((a.x - mean) * rstd, g0.x, be0.x);
    o0.y = fmaf((a.y - mean) * rstd, g0.y, be0.y);
    o0.z = fmaf((a.z - mean) * rstd, g0.z, be0.z);
    o0.w = fmaf((a.w - mean) * rstd, g0.w, be0.w);
    o1.x = fmaf((c.x - mean) * rstd, g1.x, be1.x);
    o1.y = fmaf((c.y - mean) * rstd, g1.y, be1.y);
    o1.z = fmaf((c.z - mean) * rstd, g1.z, be1.z);
    o1.w = fmaf((c.w - mean) * rstd, g1.w, be1.w);
    float* out = hn + ((size_t)b * T + t) * D;
    *((float4*)out + lane * 2) = o0;
    *((float4*)out + lane * 2 + 1) = o1;
}

// ---------------------------------------------------------------------------
// K4: head GEMM  logits[m][s] = sum_k hn[m][k]*head_W[s][k] + head_b[s]
// ---------------------------------------------------------------------------
__global__ __launch_bounds__(256) void k_head(const float* __restrict__ hn,
                                              const float* __restrict__ hw,
                                              const float* __restrict__ hb,
                                              float* __restrict__ out) {
    int m0 = blockIdx.x * 64;
    int tid = threadIdx.x;
    int tx = tid & 15, ty = tid >> 4;

    __shared__ float As[32][68];
    __shared__ float Bs[32][68];
    float acc[4][4] = {};

    for (int k0 = 0; k0 < D; k0 += 32) {
        int mm = tid >> 3, f4k = tid & 7;
#pragma unroll
        for (int h2 = 0; h2 < 2; h2++) {
            int m = mm + h2 * 32;
            float4 a = *((const float4*)(hn + (size_t)(m0 + m) * D + k0) + f4k);
            As[f4k * 4 + 0][m] = a.x;
            As[f4k * 4 + 1][m] = a.y;
            As[f4k * 4 + 2][m] = a.z;
            As[f4k * 4 + 3][m] = a.w;
            float4 wv = *((const float4*)(hw + (size_t)m * D + k0) + f4k);
            Bs[f4k * 4 + 0][m] = wv.x;
            Bs[f4k * 4 + 1][m] = wv.y;
            Bs[f4k * 4 + 2][m] = wv.z;
            Bs[f4k * 4 + 3][m] = wv.w;
        }
        __syncthreads();
#pragma unroll
        for (int k = 0; k < 32; k++) {
            float4 a  = *(float4*)&As[k][ty * 4];
            float4 bb = *(float4*)&Bs[k][tx * 4];
            float av[4] = {a.x, a.y, a.z, a.w};
            float bv[4] = {bb.x, bb.y, bb.z, bb.w};
#pragma unroll
            for (int i = 0; i < 4; i++)
#pragma unroll
                for (int j = 0; j < 4; j++) acc[i][j] = fmaf(av[i], bv[j], acc[i][j]);
        }
        __syncthreads();
    }
    float* o = out + (size_t)m0 * S;
#pragma unroll
    for (int i = 0; i < 4; i++) {
        int m = ty * 4 + i;
        float4 v;
        v.x = acc[i][0] + hb[tx * 4 + 0];
        v.y = acc[i][1] + hb[tx * 4 + 1];
        v.z = acc[i][2] + hb[tx * 4 + 2];
        v.w = acc[i][3] + hb[tx * 4 + 3];
        *(float4*)(o + (size_t)m * S + tx * 4) = v;
    }
}

// ---------------------------------------------------------------------------
extern "C" void kernel_launch(void* const* d_in, const int* in_sizes, int n_in,
                              void* d_out, int out_size, void* d_ws, size_t ws_size,
                              hipStream_t stream) {
    const int*   x      = (const int*)d_in[0];
    const float* emb    = (const float*)d_in[1];
    const float* W_ih   = (const float*)d_in[2];
    const float* W_hh   = (const float*)d_in[3];
    const float* bvec   = (const float*)d_in[4];
    const float* gamma  = (const float*)d_in[5];
    const float* beta   = (const float*)d_in[6];
    const float* head_W = (const float*)d_in[7];
    const float* head_b = (const float*)d_in[8];

    float* logits = (float*)d_out;                      // [B,T,S]
    float* hn     = (float*)d_out + (size_t)B * T * S;  // [B,T,D]

    char* ws = (char*)d_ws;
    unsigned short* Wpk  = (unsigned short*)ws;
    float*          bpk  = (float*)(ws + WPK_BYTES);
    unsigned short* hemb = (unsigned short*)(ws + WPK_BYTES + BPK_BYTES);
    unsigned short* hbuf = (unsigned short*)(ws + WPK_BYTES + BPK_BYTES + HEMB_BYTES);
    float*          hfin = (float*)(ws + WPK_BYTES + BPK_BYTES + HEMB_BYTES + HBUF_BYTES);
    unsigned*       cnt  = (unsigned*)(ws + WPK_BYTES + BPK_BYTES + HEMB_BYTES + HBUF_BYTES + HFIN_BYTES);

    k_zero<<<dim3(1), 1, 0, stream>>>(cnt);
    k_pack<<<dim3(L * 2048), 256, 0, stream>>>(W_ih, W_hh, bvec, Wpk, bpk);
    k_embed<<<dim3(T * B / 2), 256, 0, stream>>>(x, emb, hemb);

    k_scan<<<dim3(NBLK), dim3(64), 0, stream>>>(Wpk, bpk, hemb, hbuf, hfin, cnt);

    k_ln<<<dim3(B * T / 4), 256, 0, stream>>>(hfin, gamma, beta, hn);
    k_head<<<dim3(B * T / 64), 256, 0, stream>>>(hn, head_W, head_b, logits);
}

// Round 8
// 4390.523 us; speedup vs baseline: 2.6759x; 2.6759x over previous
//
#include <hip/hip_runtime.h>
#include <hip/hip_bf16.h>
#include <math.h>

// Problem constants
constexpr int B = 64, T = 128, D = 512, L = 9, S = 64;
constexpr int G = 4 * D;      // 2048 gate rows per layer
constexpr int NBLK = L * 32;  // 288 persistent blocks

typedef __attribute__((ext_vector_type(8))) short short8;          // 8 bf16 = 4 VGPR
typedef __attribute__((ext_vector_type(8))) unsigned short ushort8;
typedef __attribute__((ext_vector_type(4))) float f32x4;

// ---------------------------------------------------------------------------
// Workspace layout (bytes):
//  Wpk  [L][2048][1024] bf16  rows remapped rr=4*d+gate; k<512=W_ih, k>=512=W_hh
//  bpk  [L][2048] f32         same row remap
//  hemb [T][B][D] bf16
//  hbuf [L][2][B][D] bf16     parity ping-pong h state per layer (MALL-coherent)
//  hfin [T][B][D] f32         layer-8 h history (feeds LayerNorm)
//  cnt  [1] u32               grid barrier ticket counter
// ---------------------------------------------------------------------------
constexpr size_t WPK_BYTES  = (size_t)L * 2048 * 1024 * 2;   // 37,748,736
constexpr size_t BPK_BYTES  = (size_t)L * 2048 * 4;          // 73,728
constexpr size_t HEMB_BYTES = (size_t)T * B * D * 2;         // 8,388,608
constexpr size_t HBUF_BYTES = (size_t)L * 2 * B * D * 2;     // 1,179,648
constexpr size_t HFIN_BYTES = (size_t)T * B * D * 4;         // 16,777,216

// ---------------------------------------------------------------------------
// K0: pack weights+bias to bf16, fused [ih|hh] K-space, remapped rows.
// ---------------------------------------------------------------------------
__global__ __launch_bounds__(256) void k_pack(const float* __restrict__ W_ih,
                                              const float* __restrict__ W_hh,
                                              const float* __restrict__ bsrc,
                                              unsigned short* __restrict__ Wpk,
                                              float* __restrict__ bpk) {
    int rr = blockIdx.x;
    int l  = rr >> 11;
    int rl = rr & 2047;
    int g  = rl & 3, dd = rl >> 2;
    int srow = g * D + dd;  // source row within layer (gate-major)
    int k = threadIdx.x * 4;
    const float* src = (k < D) ? (W_ih + ((size_t)l * G + srow) * D + k)
                               : (W_hh + ((size_t)l * G + srow) * D + (k - D));
    float4 v = *(const float4*)src;
    __hip_bfloat16 b0 = __float2bfloat16(v.x), b1 = __float2bfloat16(v.y),
                   b2 = __float2bfloat16(v.z), b3 = __float2bfloat16(v.w);
    ushort4 pk;
    pk.x = *(unsigned short*)&b0; pk.y = *(unsigned short*)&b1;
    pk.z = *(unsigned short*)&b2; pk.w = *(unsigned short*)&b3;
    *(ushort4*)(Wpk + ((size_t)l * 2048 + rl) * 1024 + k) = pk;
    if (threadIdx.x == 0) bpk[(size_t)l * 2048 + rl] = bsrc[(size_t)l * G + srow];
}

// ---------------------------------------------------------------------------
// K1a: zero the grid-barrier counter (each call: deterministic across replays)
// ---------------------------------------------------------------------------
__global__ void k_zero(unsigned* __restrict__ cnt) { *cnt = 0u; }

// ---------------------------------------------------------------------------
// K1: embedding gather -> hemb [t][b][d] bf16.
// ---------------------------------------------------------------------------
__global__ __launch_bounds__(256) void k_embed(const int* __restrict__ x,
                                               const float* __restrict__ emb,
                                               unsigned short* __restrict__ hemb) {
    int row = blockIdx.x * 2 + (threadIdx.x >> 7);  // row = t*B + b
    int t = row >> 6, b = row & 63;
    int d0 = (threadIdx.x & 127) * 4;
    int xi = x[b * T + t];
    float4 v = *(const float4*)(emb + (size_t)xi * D + d0);
    __hip_bfloat16 b0 = __float2bfloat16(v.x), b1 = __float2bfloat16(v.y),
                   b2 = __float2bfloat16(v.z), b3 = __float2bfloat16(v.w);
    ushort4 pk;
    pk.x = *(unsigned short*)&b0; pk.y = *(unsigned short*)&b1;
    pk.z = *(unsigned short*)&b2; pk.w = *(unsigned short*)&b3;
    *(ushort4*)(hemb + (size_t)row * D + d0) = pk;
}

// ---------------------------------------------------------------------------
// K2: persistent scan kernel.
// Grid = 288 one-wave blocks, pinned to (l = bid>>5, bt = bid&31); output
// tile = 64 batches x 64 wrows.  Diagonals separated by a ticket barrier
// built ONLY from relaxed system-scope atomics (no acquire/release fences ->
// no buffer_inv/wbl2 -> W stays L2-resident the whole kernel).
// Cross-XCD h state: stores AND loads are relaxed system-scope b64 atomics
// (emitted as global_store/load_dwordx2 sc0 sc1: straight to/from the
// coherence point, no cache-maintenance instructions).
// Weights/bias: normal cached loads (read-only -> never stale).
// Main loop: 2-deep register ring, fully unrolled, sched_barrier(0) pins
// next-step loads before current-step MFMAs.  32 MFMA/step, BK=64.
// acc[rt][wc] regs = gates i,f,g,o of cell (dd=bt*16+wc*4+fq, bb=rt*16+fr);
// c state lives in registers for the whole 128-step sequence.
// ---------------------------------------------------------------------------
struct HF { short8 f[2][4]; };  // [kc][rt]
struct WF { short8 f[2][4]; };  // [kc][wc]

__device__ __forceinline__ HF load_h(const unsigned short* hb,
                                     const unsigned short* hp,
                                     int s, int fr, int fq) {
    HF r;
    const int k0 = s * 64;
    const unsigned short* hx = (k0 < D) ? hb : hp;
    const int kk = (k0 & (D - 1)) + fq * 8;
#pragma unroll
    for (int kc = 0; kc < 2; kc++)
#pragma unroll
        for (int rt = 0; rt < 4; rt++) {
            unsigned long long* p = (unsigned long long*)(hx +
                (size_t)(rt * 16 + fr) * D + kk + kc * 32);
            union { unsigned long long u[2]; short8 v; } tmp;
            tmp.u[0] = __hip_atomic_load(p, __ATOMIC_RELAXED, __HIP_MEMORY_SCOPE_SYSTEM);
            tmp.u[1] = __hip_atomic_load(p + 1, __ATOMIC_RELAXED, __HIP_MEMORY_SCOPE_SYSTEM);
            r.f[kc][rt] = tmp.v;
        }
    return r;
}

__device__ __forceinline__ WF load_w(const unsigned short* wbase,
                                     int s, int fr, int fq) {
    WF r;
    const int k0 = s * 64;
#pragma unroll
    for (int kc = 0; kc < 2; kc++)
#pragma unroll
        for (int wc = 0; wc < 4; wc++)
            r.f[kc][wc] = *(const short8*)(wbase + (size_t)(wc * 16 + fr) * 1024 +
                                           k0 + kc * 32 + fq * 8);
    return r;
}

__device__ __forceinline__ void compute_step(f32x4 acc[4][4], const WF& w, const HF& h) {
#pragma unroll
    for (int kc = 0; kc < 2; kc++)
#pragma unroll
        for (int wc = 0; wc < 4; wc++)
#pragma unroll
            for (int rt = 0; rt < 4; rt++)
                acc[rt][wc] = __builtin_amdgcn_mfma_f32_16x16x32_bf16(
                    w.f[kc][wc], h.f[kc][rt], acc[rt][wc], 0, 0, 0);
}

template <int NS>
__device__ __forceinline__ void gemm_pipe(f32x4 acc[4][4],
                                          const unsigned short* __restrict__ hb,
                                          const unsigned short* __restrict__ hp,
                                          const unsigned short* __restrict__ wbase,
                                          int fr, int fq) {
    HF h[2];
    WF w[2];
    h[0] = load_h(hb, hp, 0, fr, fq);
    w[0] = load_w(wbase, 0, fr, fq);
#pragma unroll
    for (int s = 0; s < NS; ++s) {
        if (s + 1 < NS) {
            h[(s + 1) & 1] = load_h(hb, hp, s + 1, fr, fq);
            w[(s + 1) & 1] = load_w(wbase, s + 1, fr, fq);
        }
        __builtin_amdgcn_sched_barrier(0);
        compute_step(acc, w[s & 1], h[s & 1]);
    }
}

__global__ __launch_bounds__(64) void k_scan(const unsigned short* __restrict__ Wpk,
                                             const float* __restrict__ bpk,
                                             const unsigned short* __restrict__ hemb,
                                             unsigned short* __restrict__ hbuf,
                                             float* __restrict__ hfin,
                                             unsigned* __restrict__ cnt) {
    const int bid = blockIdx.x;
    const int l   = bid >> 5;   // layer 0..8
    const int bt  = bid & 31;   // row chunk
    const int lane = threadIdx.x;
    const int fr = lane & 15, fq = lane >> 4;

    const unsigned short* wbase = Wpk + ((size_t)l * 2048 + (size_t)bt * 64) * 1024;

    // bias: dd = bt*16 + wc*4 + fq, 4 gates each (constant per block+lane)
    float4 bias4[4];
#pragma unroll
    for (int wc = 0; wc < 4; wc++)
        bias4[wc] = *(const float4*)(bpk + (size_t)l * 2048 + ((bt * 16 + wc * 4 + fq) << 2));

    float c_reg[4][4];
#pragma unroll
    for (int i = 0; i < 4; i++)
#pragma unroll
        for (int j = 0; j < 4; j++) c_reg[i][j] = 0.f;

    __shared__ unsigned short hst[64][16];  // bf16 h staging for coalesced store
    __shared__ float fst[64][16];           // f32 staging for hfin (l==8)

    for (int d = 0; d < L + T - 1; ++d) {
        const int t = d - l;
        if (t >= 0 && t < T) {
            const unsigned short* hb = (l == 0)
                ? (hemb + (size_t)t * B * D)
                : (hbuf + ((size_t)(l - 1) * 2 + (t & 1)) * B * D);
            const unsigned short* hp = hbuf + ((size_t)l * 2 + ((t - 1) & 1)) * B * D;

            f32x4 acc[4][4];
#pragma unroll
            for (int i = 0; i < 4; i++)
#pragma unroll
                for (int j = 0; j < 4; j++) acc[i][j] = f32x4{0.f, 0.f, 0.f, 0.f};

            if (t > 0) gemm_pipe<16>(acc, hb, hp, wbase, fr, fq);
            else       gemm_pipe<8>(acc, hb, hp, wbase, fr, fq);

            // Epilogue: acc[rt][wc] = (i,f,g,o) of cell (dd, bb) in-lane.
            unsigned short* hout = hbuf + ((size_t)l * 2 + (t & 1)) * B * D;
#pragma unroll
            for (int rt = 0; rt < 4; rt++) {
#pragma unroll
                for (int wc = 0; wc < 4; wc++) {
                    float gi = acc[rt][wc].x + bias4[wc].x;
                    float gf = acc[rt][wc].y + bias4[wc].y;
                    float gg = acc[rt][wc].z + bias4[wc].z;
                    float go = acc[rt][wc].w + bias4[wc].w;
                    float si = 1.f / (1.f + __expf(-gi));
                    float sf = 1.f / (1.f + __expf(-gf));
                    float so = 1.f / (1.f + __expf(-go));
                    float tg = tanhf(gg);
                    float cn = (t > 0) ? fmaf(sf, c_reg[rt][wc], si * tg) : (si * tg);
                    c_reg[rt][wc] = cn;
                    float hv = so * tanhf(cn);
                    __hip_bfloat16 hvb = __float2bfloat16(hv);
                    hst[rt * 16 + fr][wc * 4 + fq] = *(unsigned short*)&hvb;
                    if (l == 8) fst[rt * 16 + fr][wc * 4 + fq] = hv;
                }
            }
            __syncthreads();
            // Coalesced stores to the coherence point: relaxed system-scope
            // b64 atomic stores (emit global_store_dwordx2 sc0 sc1; no fence).
            // lane = batch row, 16 dd values = 32 B per lane.
            {
                unsigned short* dst = hout + (size_t)lane * D + bt * 16;
#pragma unroll
                for (int j = 0; j < 4; j++) {
                    unsigned long long v = *(const unsigned long long*)&hst[lane][j * 4];
                    __hip_atomic_store((unsigned long long*)(dst + j * 4), v,
                                       __ATOMIC_RELAXED, __HIP_MEMORY_SCOPE_SYSTEM);
                }
            }
            if (l == 8) {
                float* dst = hfin + ((size_t)t * B + lane) * D + bt * 16;
#pragma unroll
                for (int j = 0; j < 4; j++)
                    *(float4*)(dst + j * 4) = *(const float4*)&fst[lane][j * 4];
            }
            __syncthreads();
        }
        // ---- Ticket barrier: relaxed system atomics only (no cache inv) ----
        asm volatile("s_waitcnt vmcnt(0)" ::: "memory");
        if (lane == 0) {
            __hip_atomic_fetch_add(cnt, 1u, __ATOMIC_RELAXED, __HIP_MEMORY_SCOPE_SYSTEM);
            const unsigned tgt = (unsigned)NBLK * (unsigned)(d + 1);
            while (__hip_atomic_load(cnt, __ATOMIC_RELAXED, __HIP_MEMORY_SCOPE_SYSTEM) < tgt)
                __builtin_amdgcn_s_sleep(8);
        }
        __syncthreads();
        __builtin_amdgcn_sched_barrier(0);
        asm volatile("" ::: "memory");
    }
}

// ---------------------------------------------------------------------------
// K3: LayerNorm.  hfin [t*B+b][D] f32 -> hn [b*T+t][D] f32.  1 wave per row.
// ---------------------------------------------------------------------------
__global__ __launch_bounds__(256) void k_ln(const float* __restrict__ hfin,
                                            const float* __restrict__ gamma,
                                            const float* __restrict__ beta,
                                            float* __restrict__ hn) {
    int row  = blockIdx.x * 4 + (threadIdx.x >> 6);  // t*B + b
    int lane = threadIdx.x & 63;
    int t = row >> 6, b = row & 63;
    const float* in = hfin + (size_t)row * D;
    float4 a = *((const float4*)in + lane * 2);
    float4 c = *((const float4*)in + lane * 2 + 1);
    float s1 = a.x + a.y + a.z + a.w + c.x + c.y + c.z + c.w;
    float s2 = a.x * a.x + a.y * a.y + a.z * a.z + a.w * a.w +
               c.x * c.x + c.y * c.y + c.z * c.z + c.w * c.w;
#pragma unroll
    for (int m = 1; m < 64; m <<= 1) {
        s1 += __shfl_xor(s1, m);
        s2 += __shfl_xor(s2, m);
    }
    float mean = s1 / D;
    float rstd = rsqrtf(s2 / D - mean * mean + 1e-5f);
    float4 g0 = *((const float4*)gamma + lane * 2);
    float4 g1 = *((const float4*)gamma + lane * 2 + 1);
    float4 be0 = *((const float4*)beta + lane * 2);
    float4 be1 = *((const float4*)beta + lane * 2 + 1);
    float4 o0, o1;
    o0.x = fmaf((a.x - mean) * rstd, g0.x, be0.x);
    o0.y = fmaf((a.y - mean) * rstd, g0.y, be0.y);
    o0.z = fmaf((a.z - mean) * rstd, g0.z, be0.z);
    o0.w = fmaf((a.w - mean) * rstd, g0.w, be0.w);
    o1.x = fmaf((c.x - mean) * rstd, g1.x, be1.x);
    o1.y = fmaf((c.y - mean) * rstd, g1.y, be1.y);
    o1.z = fmaf((c.z - mean) * rstd, g1.z, be1.z);
    o1.w = fmaf((c.w - mean) * rstd, g1.w, be1.w);
    float* out = hn + ((size_t)b * T + t) * D;
    *((float4*)out + lane * 2) = o0;
    *((float4*)out + lane * 2 + 1) = o1;
}

// ---------------------------------------------------------------------------
// K4: head GEMM  logits[m][s] = sum_k hn[m][k]*head_W[s][k] + head_b[s]
// ---------------------------------------------------------------------------
__global__ __launch_bounds__(256) void k_head(const float* __restrict__ hn,
                                              const float* __restrict__ hw,
                                              const float* __restrict__ hb,
                                              float* __restrict__ out) {
    int m0 = blockIdx.x * 64;
    int tid = threadIdx.x;
    int tx = tid & 15, ty = tid >> 4;

    __shared__ float As[32][68];
    __shared__ float Bs[32][68];
    float acc[4][4] = {};

    for (int k0 = 0; k0 < D; k0 += 32) {
        int mm = tid >> 3, f4k = tid & 7;
#pragma unroll
        for (int h2 = 0; h2 < 2; h2++) {
            int m = mm + h2 * 32;
            float4 a = *((const float4*)(hn + (size_t)(m0 + m) * D + k0) + f4k);
            As[f4k * 4 + 0][m] = a.x;
            As[f4k * 4 + 1][m] = a.y;
            As[f4k * 4 + 2][m] = a.z;
            As[f4k * 4 + 3][m] = a.w;
            float4 wv = *((const float4*)(hw + (size_t)m * D + k0) + f4k);
            Bs[f4k * 4 + 0][m] = wv.x;
            Bs[f4k * 4 + 1][m] = wv.y;
            Bs[f4k * 4 + 2][m] = wv.z;
            Bs[f4k * 4 + 3][m] = wv.w;
        }
        __syncthreads();
#pragma unroll
        for (int k = 0; k < 32; k++) {
            float4 a  = *(float4*)&As[k][ty * 4];
            float4 bb = *(float4*)&Bs[k][tx * 4];
            float av[4] = {a.x, a.y, a.z, a.w};
            float bv[4] = {bb.x, bb.y, bb.z, bb.w};
#pragma unroll
            for (int i = 0; i < 4; i++)
#pragma unroll
                for (int j = 0; j < 4; j++) acc[i][j] = fmaf(av[i], bv[j], acc[i][j]);
        }
        __syncthreads();
    }
    float* o = out + (size_t)m0 * S;
#pragma unroll
    for (int i = 0; i < 4; i++) {
        int m = ty * 4 + i;
        float4 v;
        v.x = acc[i][0] + hb[tx * 4 + 0];
        v.y = acc[i][1] + hb[tx * 4 + 1];
        v.z = acc[i][2] + hb[tx * 4 + 2];
        v.w = acc[i][3] + hb[tx * 4 + 3];
        *(float4*)(o + (size_t)m * S + tx * 4) = v;
    }
}

// ---------------------------------------------------------------------------
extern "C" void kernel_launch(void* const* d_in, const int* in_sizes, int n_in,
                              void* d_out, int out_size, void* d_ws, size_t ws_size,
                              hipStream_t stream) {
    const int*   x      = (const int*)d_in[0];
    const float* emb    = (const float*)d_in[1];
    const float* W_ih   = (const float*)d_in[2];
    const float* W_hh   = (const float*)d_in[3];
    const float* bvec   = (const float*)d_in[4];
    const float* gamma  = (const float*)d_in[5];
    const float* beta   = (const float*)d_in[6];
    const float* head_W = (const float*)d_in[7];
    const float* head_b = (const float*)d_in[8];

    float* logits = (float*)d_out;                      // [B,T,S]
    float* hn     = (float*)d_out + (size_t)B * T * S;  // [B,T,D]

    char* ws = (char*)d_ws;
    unsigned short* Wpk  = (unsigned short*)ws;
    float*          bpk  = (float*)(ws + WPK_BYTES);
    unsigned short* hemb = (unsigned short*)(ws + WPK_BYTES + BPK_BYTES);
    unsigned short* hbuf = (unsigned short*)(ws + WPK_BYTES + BPK_BYTES + HEMB_BYTES);
    float*          hfin = (float*)(ws + WPK_BYTES + BPK_BYTES + HEMB_BYTES + HBUF_BYTES);
    unsigned*       cnt  = (unsigned*)(ws + WPK_BYTES + BPK_BYTES + HEMB_BYTES + HBUF_BYTES + HFIN_BYTES);

    k_zero<<<dim3(1), 1, 0, stream>>>(cnt);
    k_pack<<<dim3(L * 2048), 256, 0, stream>>>(W_ih, W_hh, bvec, Wpk, bpk);
    k_embed<<<dim3(T * B / 2), 256, 0, stream>>>(x, emb, hemb);

    k_scan<<<dim3(NBLK), dim3(64), 0, stream>>>(Wpk, bpk, hemb, hbuf, hfin, cnt);

    k_ln<<<dim3(B * T / 4), 256, 0, stream>>>(hfin, gamma, beta, hn);
    k_head<<<dim3(B * T / 64), 256, 0, stream>>>(hn, head_W, head_b, logits);
}